// Round 3
// baseline (260.196 us; speedup 1.0000x reference)
//
#include <hip/hip_runtime.h>

#define HID 128
#define PTS 32
#define FRAGS_PER_W 2048           // 4 mw * 8 ks8 * 64 lanes
#define WS_ELEMS (FRAGS_PER_W * 8) // ushorts per weight plane

typedef float v4f  __attribute__((ext_vector_type(4)));
typedef float v16f __attribute__((ext_vector_type(16)));
typedef short s8v  __attribute__((ext_vector_type(8)));         // 8 bf16 (MFMA A/B frag)

__device__ __forceinline__ unsigned short f2bf(float f) {       // RNE (prep only)
    unsigned u = __builtin_bit_cast(unsigned, f);
    u = (u + 0x7FFFu + ((u >> 16) & 1u)) >> 16;
    return (unsigned short)u;
}

// --- packed fp32 -> 2x bf16 (RNE), 1 instr on gfx950 ---
#if __has_builtin(__builtin_amdgcn_cvt_pk_bf16_f32)
typedef __bf16 bf16x2 __attribute__((ext_vector_type(2)));
__device__ __forceinline__ unsigned pk2(float f0, float f1) {   // (bf(f1)<<16)|bf(f0)
    return __builtin_bit_cast(unsigned, __builtin_amdgcn_cvt_pk_bf16_f32(f0, f1));
}
#else
__device__ __forceinline__ unsigned pk2(float f0, float f1) {
    unsigned u0 = __builtin_bit_cast(unsigned, f0);
    unsigned u1 = __builtin_bit_cast(unsigned, f1);
    u0 += 0x7FFFu + ((u0 >> 16) & 1u);
    u1 += 0x7FFFu + ((u1 >> 16) & 1u);
    return __builtin_amdgcn_perm(u1, u0, 0x07060302u);
}
#endif
__device__ __forceinline__ uint2 pk4(const float* f) {
    uint2 h;
    h.x = pk2(f[0], f[1]);
    h.y = pk2(f[2], f[3]);
    return h;
}

// tanh(x) = 1 - 2/(exp(2x)+1); single mul + v_exp + v_rcp
__device__ __forceinline__ float fast_tanh(float x) {
#if __has_builtin(__builtin_amdgcn_exp2f)
    float e = __builtin_amdgcn_exp2f(x * 2.885390081777927f);   // 2*log2(e)
#else
    float e = __expf(2.0f * x);
#endif
    float r = __builtin_amdgcn_rcpf(e + 1.0f);
    return 1.0f - 2.0f * r;
}

// sB: [NC*32 rows] x 128 bf16 cols, 256B row stride, NO pad.
// XOR-swizzle (T2): byte ^= (row&15)<<4 — bijective within each row, preserves
// 8B/16B granule alignment (touches bits 4-7 only). Column-strided accesses
// (epilogue 8B writes at row=l31, fixed col; B-frag 16B reads at row=l31,
// fixed col) spread across all 16 slots -> 2-way max (free, m136). This
// replaces the old KP=136 pad (which left epilogue writes 4-way conflicted)
// and shrinks sB 34,816 -> 32,768 B, lifting occupancy 4 -> 5 blocks/CU.
__device__ __forceinline__ void* sb_at(unsigned short* sBh, int row, int colh) {
    return (char*)sBh + (row << 8) + (((colh << 1)) ^ ((row & 15) << 4));
}

// One-time: W1/W2 -> RNE bf16 A-fragments for 32x32x16, frag-linear in d_ws.
// A[m][k] = W[k][m]; m = mw*32 + (lane&31), k = ks8*16 + (lane>>5)*8 + i.
// frag idx r = mw*512 + ks8*64 + lane. Planes: [W1][W2].
__global__ __launch_bounds__(256) void prep_w_kernel(
    const float* __restrict__ W1, const float* __restrict__ W2,
    unsigned short* __restrict__ ws, float* __restrict__ out)
{
    if (blockIdx.x == 0 && threadIdx.x < 2) out[threadIdx.x] = 0.0f;
    const int t = blockIdx.x * 256 + threadIdx.x;   // 0..4095
    const int w = t >> 11;
    const int r = t & 2047;
    const int mw = r >> 9;
    const int ks8 = (r >> 6) & 7;
    const int lane = r & 63;
    const int m = mw * 32 + (lane & 31);
    const int kb = ks8 * 16 + (lane >> 5) * 8;
    const float* W = w ? W2 : W1;
    s8v hv;
    #pragma unroll
    for (int i = 0; i < 8; ++i)
        hv[i] = (short)f2bf(W[(kb + i) * HID + m]);
    *(s8v*)&ws[((size_t)w * FRAGS_PER_W + r) * 8] = hv;
}

// Stall-bound per counters (real MFMA ~24%, real VALU ~27% after the gfx94x
// 2x-formula correction; both pipes idle >50%): the lever is occupancy.
// KP-pad -> XOR-swizzle drops LDS to exactly 32KB -> 5 blocks/CU (was 4),
// sPart aliased onto sB (extra barrier after last LDS read covers the reuse).
// NC=4: interior (lap readout). NC=1: boundary (value only).
// Wave = m-tile mw (32 j) x all n-tiles (==channels). C/D (m101, verified):
// col=lane&31 (=p), row=(reg&3)+8*(reg>>2)+4*(lane>>5) (=j offset).
template <int NC>
__device__ __forceinline__ void run_pinn(
    const float* __restrict__ xy, const float* __restrict__ tgt,
    const float* __restrict__ W0, const float* __restrict__ b0,
    const float* __restrict__ b1, const float* __restrict__ b2,
    const float* __restrict__ W3, const float* __restrict__ b3,
    const unsigned short* __restrict__ ws, float* __restrict__ out_slot,
    float scale, int pbase, unsigned short* sBh, float* sPart)
{
    const int tid  = threadIdx.x;
    const int lane = tid & 63;
    const int mw   = tid >> 6;      // wave = m-tile (32 j-rows)
    const int l31  = lane & 31;
    const int kh   = lane >> 5;     // k-half of frag / +4*kh j-offset in C

    // ---- layer 0: 2 -> 128, VALU, RNE-bf16 store into sB ----
    {
        const int tj = tid & 31, tp = tid >> 5;
        const int j0 = tj * 4, p0 = tp * 4;
        float wx[4], wy[4], bb[4], m2s2[4];
        #pragma unroll
        for (int jj = 0; jj < 4; ++jj) {
            wx[jj] = W0[j0 + jj];
            wy[jj] = W0[HID + j0 + jj];
            bb[jj] = b0[j0 + jj];
            m2s2[jj] = -2.0f * fmaf(wx[jj], wx[jj], wy[jj] * wy[jj]);
        }
        #pragma unroll
        for (int pp = 0; pp < 4; ++pp) {
            const int p = p0 + pp;
            const float2 t2 = ((const float2*)xy)[pbase + p];
            float chv[NC][4];                   // [c][jj]
            #pragma unroll
            for (int jj = 0; jj < 4; ++jj) {
                float z = fmaf(t2.x, wx[jj], fmaf(t2.y, wy[jj], bb[jj]));
                float a = fast_tanh(z);
                chv[0][jj] = a;
                if (NC == 4) {
                    float t = fmaf(-a, a, 1.0f);
                    chv[1][jj] = t * wx[jj];
                    chv[2][jj] = t * wy[jj];
                    chv[3][jj] = (a * t) * m2s2[jj];    // z_lap = 0 at layer 0
                }
            }
            #pragma unroll
            for (int c = 0; c < NC; ++c)
                *(uint2*)sb_at(sBh, c * 32 + p, j0) = pk4(chv[c]);
        }
    }
    __syncthreads();

    v16f acc[NC];   // [ntile == channel]

    // ---- hidden layers: D = W(A-op 32x32, bf16) x Act(B-op), 1 product ----
    #pragma unroll
    for (int L = 0; L < 2; ++L) {
        const unsigned short* wsp = ws + (size_t)L * WS_ELEMS;

        // full layer W resident: 8 s8v = 32 VGPR, one load burst, no dbuf
        s8v wf[8];
        #pragma unroll
        for (int q = 0; q < 8; ++q)
            wf[q] = *(const s8v*)&wsp[(size_t)(mw * 512 + q * 64 + lane) * 8];

        #pragma unroll
        for (int nt = 0; nt < NC; ++nt) acc[nt] = (v16f)0.0f;

        #pragma unroll
        for (int q = 0; q < 8; ++q) {           // q == ks8 (16-wide k-block)
            const int koff = q * 16 + kh * 8;   // B: k=(lane>>5)*8+i
            #pragma unroll
            for (int nt = 0; nt < NC; ++nt) {
                s8v bh = *(const s8v*)sb_at(sBh, nt * 32 + l31, koff);
                acc[nt] = __builtin_amdgcn_mfma_f32_32x32x16_bf16(
                    wf[q], bh, acc[nt], 0, 0, 0);
            }
        }

        if (L == 0) {
            __syncthreads();        // all waves done reading sB
            // epilogue L0: channels -> sB
            #pragma unroll
            for (int g = 0; g < 4; ++g) {       // reg-groups: j = j0g + (r&3)
                const int j0g = mw * 32 + 8 * g + 4 * kh;
                const v4f bb = *(const v4f*)&b1[j0g];
                float chv[NC][4];               // [c][r]
                #pragma unroll
                for (int r = 0; r < 4; ++r) {
                    float z = acc[0][g * 4 + r] + bb[r];
                    float a = fast_tanh(z);
                    chv[0][r] = a;
                    if (NC == 4) {
                        float t = fmaf(-a, a, 1.0f);
                        float zx = acc[1][g * 4 + r], zy = acc[2][g * 4 + r],
                              zl = acc[3][g * 4 + r];
                        float s2 = fmaf(zx, zx, zy * zy);
                        float u  = fmaf(-(a + a), s2, zl);
                        chv[1][r] = t * zx;
                        chv[2][r] = t * zy;
                        chv[3][r] = t * u;
                    }
                }
                #pragma unroll
                for (int c = 0; c < NC; ++c)
                    *(uint2*)sb_at(sBh, c * 32 + l31, j0g) = pk4(chv[c]);
            }
            __syncthreads();
        }
    }

    // ---- fused readout on the L=1 acc: chain + W3 dot entirely in registers ----
    {
        float part = 0.0f;
        #pragma unroll
        for (int g = 0; g < 4; ++g) {
            const int j0g = mw * 32 + 8 * g + 4 * kh;
            const v4f bb = *(const v4f*)&b2[j0g];
            const v4f w3 = *(const v4f*)&W3[j0g];
            #pragma unroll
            for (int r = 0; r < 4; ++r) {
                float z = acc[0][g * 4 + r] + bb[r];
                float a = fast_tanh(z);
                float v;
                if (NC == 1) {
                    v = a;                              // pred = a . W3
                } else {
                    float t = fmaf(-a, a, 1.0f);
                    float zx = acc[1][g * 4 + r], zy = acc[2][g * 4 + r],
                          zl = acc[3][g * 4 + r];
                    float s2 = fmaf(zx, zx, zy * zy);
                    v = t * fmaf(-(a + a), s2, zl);     // pred = lap . W3
                }
                part = fmaf(v, w3[r], part);
            }
        }
        part += __shfl_xor(part, 32, 64);       // combine the two kh halves
        // sPart aliases sB: wait until every wave's L2 B-frag reads are done
        __syncthreads();
        if (kh == 0) sPart[mw * 32 + l31] = part;
        __syncthreads();
        if (mw == 0) {                          // wave 0: combine 4 m-tiles/point
            const int p = l31;
            float pred = (sPart[p] + sPart[32 + p]) + (sPart[64 + p] + sPart[96 + p])
                       + ((NC == 1) ? b3[0] : 0.0f);    // lap kills b3
            float d = pred - tgt[pbase + p];
            float sq = (kh == 0) ? d * d : 0.0f;
            sq += __shfl_xor(sq, 1, 64);
            sq += __shfl_xor(sq, 2, 64);
            sq += __shfl_xor(sq, 4, 64);
            sq += __shfl_xor(sq, 8, 64);
            sq += __shfl_xor(sq, 16, 64);
            sq += __shfl_xor(sq, 32, 64);
            if (lane == 0) atomicAdd(out_slot, sq * scale);
        }
    }
}

// Fused interior+boundary: ONE uniform branch at entry (coarse-grain diamond),
// each side a clean straight-line template instantiation.
__global__ __launch_bounds__(256, 5) void pinn_mfma_kernel(
    const float* __restrict__ xy_int, const float* __restrict__ f_t,
    const float* __restrict__ xy_bd, const float* __restrict__ g_t,
    const float* __restrict__ W0, const float* __restrict__ b0,
    const float* __restrict__ b1, const float* __restrict__ b2,
    const float* __restrict__ W3, const float* __restrict__ b3,
    const unsigned short* __restrict__ ws, float* __restrict__ out,
    int gi, float scale_int, float scale_bd)
{
    extern __shared__ char smem_raw[];
    unsigned short* sBh = (unsigned short*)smem_raw;     // [4*32][128] bf16, swizzled
    float* sPart = (float*)smem_raw;                     // [128] ALIASES sB (post-barrier)

    const int b = (int)blockIdx.x;
    if (b >= gi)
        run_pinn<1>(xy_bd, g_t, W0, b0, b1, b2, W3, b3, ws,
                    out + 0, scale_bd, (b - gi) * PTS, sBh, sPart);
    else
        run_pinn<4>(xy_int, f_t, W0, b0, b1, b2, W3, b3, ws,
                    out + 1, scale_int, b * PTS, sBh, sPart);
}

extern "C" void kernel_launch(void* const* d_in, const int* in_sizes, int n_in,
                              void* d_out, int out_size, void* d_ws, size_t ws_size,
                              hipStream_t stream) {
    const float* xy_int = (const float*)d_in[0];
    const float* f      = (const float*)d_in[1];
    const float* xy_bd  = (const float*)d_in[2];
    const float* g      = (const float*)d_in[3];
    const float* W0 = (const float*)d_in[4];
    const float* b0 = (const float*)d_in[5];
    const float* W1 = (const float*)d_in[6];
    const float* b1 = (const float*)d_in[7];
    const float* W2 = (const float*)d_in[8];
    const float* b2 = (const float*)d_in[9];
    const float* W3 = (const float*)d_in[10];
    const float* b3 = (const float*)d_in[11];
    float* out = (float*)d_out;
    unsigned short* ws = (unsigned short*)d_ws;   // needs 128 KB

    const int n_int = in_sizes[0] / 2;   // 262144
    const int n_bd  = in_sizes[2] / 2;   // 16384

    prep_w_kernel<<<16, 256, 0, stream>>>(W1, W2, ws, out);

    const int smem = 4 * 32 * 128 * 2;   // 32,768 B exactly -> 5 blocks/CU
    const int gi = n_int / PTS;
    const int gb = n_bd / PTS;

    pinn_mfma_kernel<<<gi + gb, 256, smem, stream>>>(
        xy_int, f, xy_bd, g, W0, b0, b1, b2, W3, b3, ws, out,
        gi, 0.5f / (float)n_int, 0.5f / (float)n_bd);
}

// Round 4
// 192.053 us; speedup vs baseline: 1.3548x; 1.3548x over previous
//
#include <hip/hip_runtime.h>

#define HID 128
#define PTS 32
#define FRAGS_PER_W 2048           // 4 mw * 8 ks8 * 64 lanes
#define WS_ELEMS (FRAGS_PER_W * 8) // ushorts per weight plane

typedef float v4f  __attribute__((ext_vector_type(4)));
typedef float v16f __attribute__((ext_vector_type(16)));
typedef short s8v  __attribute__((ext_vector_type(8)));         // 8 bf16 (MFMA A/B frag)

__device__ __forceinline__ unsigned short f2bf(float f) {       // RNE (prep only)
    unsigned u = __builtin_bit_cast(unsigned, f);
    u = (u + 0x7FFFu + ((u >> 16) & 1u)) >> 16;
    return (unsigned short)u;
}

// --- packed fp32 -> 2x bf16 (RNE), 1 instr on gfx950 ---
#if __has_builtin(__builtin_amdgcn_cvt_pk_bf16_f32)
typedef __bf16 bf16x2 __attribute__((ext_vector_type(2)));
__device__ __forceinline__ unsigned pk2(float f0, float f1) {   // (bf(f1)<<16)|bf(f0)
    return __builtin_bit_cast(unsigned, __builtin_amdgcn_cvt_pk_bf16_f32(f0, f1));
}
#else
__device__ __forceinline__ unsigned pk2(float f0, float f1) {
    unsigned u0 = __builtin_bit_cast(unsigned, f0);
    unsigned u1 = __builtin_bit_cast(unsigned, f1);
    u0 += 0x7FFFu + ((u0 >> 16) & 1u);
    u1 += 0x7FFFu + ((u1 >> 16) & 1u);
    return __builtin_amdgcn_perm(u1, u0, 0x07060302u);
}
#endif
__device__ __forceinline__ uint2 pk4(const float* f) {
    uint2 h;
    h.x = pk2(f[0], f[1]);
    h.y = pk2(f[2], f[3]);
    return h;
}

// tanh(x) = 1 - 2/(exp(2x)+1); single mul + v_exp + v_rcp
__device__ __forceinline__ float fast_tanh(float x) {
#if __has_builtin(__builtin_amdgcn_exp2f)
    float e = __builtin_amdgcn_exp2f(x * 2.885390081777927f);   // 2*log2(e)
#else
    float e = __expf(2.0f * x);
#endif
    float r = __builtin_amdgcn_rcpf(e + 1.0f);
    return 1.0f - 2.0f * r;
}

// sB: [NC*32 rows] x 128 bf16 cols, 256B row stride, XOR-swizzled
// (byte ^= (row&15)<<4): bijective within a row, preserves 8/16B granule
// alignment. sB = exactly 32 KB (vs 34.8 KB padded).
__device__ __forceinline__ void* sb_at(unsigned short* sBh, int row, int colh) {
    return (char*)sBh + (row << 8) + (((colh << 1)) ^ ((row & 15) << 4));
}

// One-time: W1/W2 -> RNE bf16 A-fragments for 32x32x16, frag-linear in d_ws.
// A[m][k] = W[k][m]; m = mw*32 + (lane&31), k = ks8*16 + (lane>>5)*8 + i.
// frag idx r = mw*512 + ks8*64 + lane. Planes: [W1][W2].
__global__ __launch_bounds__(256) void prep_w_kernel(
    const float* __restrict__ W1, const float* __restrict__ W2,
    unsigned short* __restrict__ ws, float* __restrict__ out)
{
    if (blockIdx.x == 0 && threadIdx.x < 2) out[threadIdx.x] = 0.0f;
    const int t = blockIdx.x * 256 + threadIdx.x;   // 0..4095
    const int w = t >> 11;
    const int r = t & 2047;
    const int mw = r >> 9;
    const int ks8 = (r >> 6) & 7;
    const int lane = r & 63;
    const int m = mw * 32 + (lane & 31);
    const int kb = ks8 * 16 + (lane >> 5) * 8;
    const float* W = w ? W2 : W1;
    s8v hv;
    #pragma unroll
    for (int i = 0; i < 8; ++i)
        hv[i] = (short)f2bf(W[(kb + i) * HID + m]);
    *(s8v*)&ws[((size_t)w * FRAGS_PER_W + r) * 8] = hv;
}

// R3 POST-MORTEM: launch_bounds(256,5) capped regs at ~102 < the ~120 the
// kernel needs (56 VGPR + 64 acc on the unified file) -> acc spilled to
// scratch -> 574 MB HBM traffic, +80us. Occupancy is REGISTER-bound at 4
// blocks/CU; min-waves stays 4. This round hides the two wf VMEM bursts
// instead (T14 issue-early): L=0 burst at entry (under L0 VALU), L=1 burst
// right after the post-MFMA barrier (under epilogue VALU, reusing dead L=0
// wf registers -> peak pressure unchanged). __syncthreads drains vmcnt(0),
// so issue sites must sit BEFORE a long VALU phase, which these do.
// NC=4: interior (lap readout). NC=1: boundary (value only).
// Wave = m-tile mw (32 j) x all n-tiles (==channels). C/D (m101, verified):
// col=lane&31 (=p), row=(reg&3)+8*(reg>>2)+4*(lane>>5) (=j offset).
template <int NC>
__device__ __forceinline__ void run_pinn(
    const float* __restrict__ xy, const float* __restrict__ tgt,
    const float* __restrict__ W0, const float* __restrict__ b0,
    const float* __restrict__ b1, const float* __restrict__ b2,
    const float* __restrict__ W3, const float* __restrict__ b3,
    const unsigned short* __restrict__ ws, float* __restrict__ out_slot,
    float scale, int pbase, unsigned short* sBh, float* sPart)
{
    const int tid  = threadIdx.x;
    const int lane = tid & 63;
    const int mw   = tid >> 6;      // wave = m-tile (32 j-rows)
    const int l31  = lane & 31;
    const int kh   = lane >> 5;     // k-half of frag / +4*kh j-offset in C

    // ---- L=0 weight burst issued at ENTRY: ~600cy of L0 VALU hides it ----
    s8v wf[8];
    #pragma unroll
    for (int q = 0; q < 8; ++q)
        wf[q] = *(const s8v*)&ws[(size_t)(mw * 512 + q * 64 + lane) * 8];

    // ---- layer 0: 2 -> 128, VALU, RNE-bf16 store into sB ----
    {
        const int tj = tid & 31, tp = tid >> 5;
        const int j0 = tj * 4, p0 = tp * 4;
        float wx[4], wy[4], bb[4], m2s2[4];
        #pragma unroll
        for (int jj = 0; jj < 4; ++jj) {
            wx[jj] = W0[j0 + jj];
            wy[jj] = W0[HID + j0 + jj];
            bb[jj] = b0[j0 + jj];
            m2s2[jj] = -2.0f * fmaf(wx[jj], wx[jj], wy[jj] * wy[jj]);
        }
        #pragma unroll
        for (int pp = 0; pp < 4; ++pp) {
            const int p = p0 + pp;
            const float2 t2 = ((const float2*)xy)[pbase + p];
            float chv[NC][4];                   // [c][jj]
            #pragma unroll
            for (int jj = 0; jj < 4; ++jj) {
                float z = fmaf(t2.x, wx[jj], fmaf(t2.y, wy[jj], bb[jj]));
                float a = fast_tanh(z);
                chv[0][jj] = a;
                if (NC == 4) {
                    float t = fmaf(-a, a, 1.0f);
                    chv[1][jj] = t * wx[jj];
                    chv[2][jj] = t * wy[jj];
                    chv[3][jj] = (a * t) * m2s2[jj];    // z_lap = 0 at layer 0
                }
            }
            #pragma unroll
            for (int c = 0; c < NC; ++c)
                *(uint2*)sb_at(sBh, c * 32 + p, j0) = pk4(chv[c]);
        }
    }
    __syncthreads();

    v16f acc[NC];   // [ntile == channel]

    // ---- hidden layers: D = W(A-op 32x32, bf16) x Act(B-op) ----
    #pragma unroll
    for (int L = 0; L < 2; ++L) {
        #pragma unroll
        for (int nt = 0; nt < NC; ++nt) acc[nt] = (v16f)0.0f;

        #pragma unroll
        for (int q = 0; q < 8; ++q) {           // q == ks8 (16-wide k-block)
            const int koff = q * 16 + kh * 8;   // B: k=(lane>>5)*8+i
            #pragma unroll
            for (int nt = 0; nt < NC; ++nt) {
                s8v bh = *(const s8v*)sb_at(sBh, nt * 32 + l31, koff);
                acc[nt] = __builtin_amdgcn_mfma_f32_32x32x16_bf16(
                    wf[q], bh, acc[nt], 0, 0, 0);
            }
        }

        if (L == 0) {
            __syncthreads();        // all waves done reading sB
            // L=1 weight burst NOW: L=0 wf regs are dead (reused), and the
            // epilogue's ~500cy of VALU hides the L2 latency before the next
            // barrier's vmcnt(0) drain.
            #pragma unroll
            for (int q = 0; q < 8; ++q)
                wf[q] = *(const s8v*)&ws[WS_ELEMS + (size_t)(mw * 512 + q * 64 + lane) * 8];
            // epilogue L0: channels -> sB
            #pragma unroll
            for (int g = 0; g < 4; ++g) {       // reg-groups: j = j0g + (r&3)
                const int j0g = mw * 32 + 8 * g + 4 * kh;
                const v4f bb = *(const v4f*)&b1[j0g];
                float chv[NC][4];               // [c][r]
                #pragma unroll
                for (int r = 0; r < 4; ++r) {
                    float z = acc[0][g * 4 + r] + bb[r];
                    float a = fast_tanh(z);
                    chv[0][r] = a;
                    if (NC == 4) {
                        float t = fmaf(-a, a, 1.0f);
                        float zx = acc[1][g * 4 + r], zy = acc[2][g * 4 + r],
                              zl = acc[3][g * 4 + r];
                        float s2 = fmaf(zx, zx, zy * zy);
                        float u  = fmaf(-(a + a), s2, zl);
                        chv[1][r] = t * zx;
                        chv[2][r] = t * zy;
                        chv[3][r] = t * u;
                    }
                }
                #pragma unroll
                for (int c = 0; c < NC; ++c)
                    *(uint2*)sb_at(sBh, c * 32 + l31, j0g) = pk4(chv[c]);
            }
            __syncthreads();
        }
    }

    // ---- fused readout on the L=1 acc: chain + W3 dot entirely in registers ----
    {
        float part = 0.0f;
        #pragma unroll
        for (int g = 0; g < 4; ++g) {
            const int j0g = mw * 32 + 8 * g + 4 * kh;
            const v4f bb = *(const v4f*)&b2[j0g];
            const v4f w3 = *(const v4f*)&W3[j0g];
            #pragma unroll
            for (int r = 0; r < 4; ++r) {
                float z = acc[0][g * 4 + r] + bb[r];
                float a = fast_tanh(z);
                float v;
                if (NC == 1) {
                    v = a;                              // pred = a . W3
                } else {
                    float t = fmaf(-a, a, 1.0f);
                    float zx = acc[1][g * 4 + r], zy = acc[2][g * 4 + r],
                          zl = acc[3][g * 4 + r];
                    float s2 = fmaf(zx, zx, zy * zy);
                    v = t * fmaf(-(a + a), s2, zl);     // pred = lap . W3
                }
                part = fmaf(v, w3[r], part);
            }
        }
        part += __shfl_xor(part, 32, 64);       // combine the two kh halves
        if (kh == 0) sPart[mw * 32 + l31] = part;   // sPart is its own buffer
        __syncthreads();
        if (mw == 0) {                          // wave 0: combine 4 m-tiles/point
            const int p = l31;
            float pred = (sPart[p] + sPart[32 + p]) + (sPart[64 + p] + sPart[96 + p])
                       + ((NC == 1) ? b3[0] : 0.0f);    // lap kills b3
            float d = pred - tgt[pbase + p];
            float sq = (kh == 0) ? d * d : 0.0f;
            sq += __shfl_xor(sq, 1, 64);
            sq += __shfl_xor(sq, 2, 64);
            sq += __shfl_xor(sq, 4, 64);
            sq += __shfl_xor(sq, 8, 64);
            sq += __shfl_xor(sq, 16, 64);
            sq += __shfl_xor(sq, 32, 64);
            if (lane == 0) atomicAdd(out_slot, sq * scale);
        }
    }
}

// Fused interior+boundary: ONE uniform branch at entry (coarse-grain diamond),
// each side a clean straight-line template instantiation.
// min-waves=4: reg cap 128 fits the ~120-reg footprint (R3 lesson: 5 spills).
__global__ __launch_bounds__(256, 4) void pinn_mfma_kernel(
    const float* __restrict__ xy_int, const float* __restrict__ f_t,
    const float* __restrict__ xy_bd, const float* __restrict__ g_t,
    const float* __restrict__ W0, const float* __restrict__ b0,
    const float* __restrict__ b1, const float* __restrict__ b2,
    const float* __restrict__ W3, const float* __restrict__ b3,
    const unsigned short* __restrict__ ws, float* __restrict__ out,
    int gi, float scale_int, float scale_bd)
{
    extern __shared__ char smem_raw[];
    unsigned short* sBh = (unsigned short*)smem_raw;     // [4*32][128] bf16, swizzled (32 KB)
    float* sPart = (float*)(sBh + 4 * 32 * 128);         // [128] separate (no alias barrier)

    const int b = (int)blockIdx.x;
    if (b >= gi)
        run_pinn<1>(xy_bd, g_t, W0, b0, b1, b2, W3, b3, ws,
                    out + 0, scale_bd, (b - gi) * PTS, sBh, sPart);
    else
        run_pinn<4>(xy_int, f_t, W0, b0, b1, b2, W3, b3, ws,
                    out + 1, scale_int, b * PTS, sBh, sPart);
}

extern "C" void kernel_launch(void* const* d_in, const int* in_sizes, int n_in,
                              void* d_out, int out_size, void* d_ws, size_t ws_size,
                              hipStream_t stream) {
    const float* xy_int = (const float*)d_in[0];
    const float* f      = (const float*)d_in[1];
    const float* xy_bd  = (const float*)d_in[2];
    const float* g      = (const float*)d_in[3];
    const float* W0 = (const float*)d_in[4];
    const float* b0 = (const float*)d_in[5];
    const float* W1 = (const float*)d_in[6];
    const float* b1 = (const float*)d_in[7];
    const float* W2 = (const float*)d_in[8];
    const float* b2 = (const float*)d_in[9];
    const float* W3 = (const float*)d_in[10];
    const float* b3 = (const float*)d_in[11];
    float* out = (float*)d_out;
    unsigned short* ws = (unsigned short*)d_ws;   // needs 128 KB

    const int n_int = in_sizes[0] / 2;   // 262144
    const int n_bd  = in_sizes[2] / 2;   // 16384

    prep_w_kernel<<<16, 256, 0, stream>>>(W1, W2, ws, out);

    const int smem = 4 * 32 * 128 * 2 + 128 * 4;  // 33,280 B; 4 blocks/CU (reg-bound)
    const int gi = n_int / PTS;
    const int gb = n_bd / PTS;

    pinn_mfma_kernel<<<gi + gb, 256, smem, stream>>>(
        xy_int, f, xy_bd, g, W0, b0, b1, b2, W3, b3, ws, out,
        gi, 0.5f / (float)n_int, 0.5f / (float)n_bd);
}